// Round 2
// baseline (2756.770 us; speedup 1.0000x reference)
//
#include <hip/hip_runtime.h>

#define NN 100000
#define EE 1600000
#define DI 128
#define HH 64
#define CO 10
#define GG 1024

// ---------------- tiny collapsed-weight kernel (1 block) ----------------
// Wf = W1@W2@W3@Wl (128x10), c1 = b1@W2@W3@Wl, c2 = b2@W3@Wl, c3 = b3@Wl
__global__ void k_small_mats(const float* __restrict__ W1, const float* __restrict__ W2,
                             const float* __restrict__ W3, const float* __restrict__ Wl,
                             const float* __restrict__ b1, const float* __restrict__ b2,
                             const float* __restrict__ b3,
                             float* __restrict__ Wf, float* __restrict__ cvec) {
    __shared__ float M3l[HH * CO];   // W3@Wl   (64x10)
    __shared__ float M23l[HH * CO];  // W2@M3l  (64x10)
    int t = threadIdx.x;
    for (int i = t; i < HH * CO; i += blockDim.x) {
        int r = i / CO, c = i % CO;
        float s = 0.f;
        for (int k = 0; k < HH; ++k) s += W3[r * HH + k] * Wl[k * CO + c];
        M3l[i] = s;
    }
    __syncthreads();
    for (int i = t; i < HH * CO; i += blockDim.x) {
        int r = i / CO, c = i % CO;
        float s = 0.f;
        for (int k = 0; k < HH; ++k) s += W2[r * HH + k] * M3l[k * CO + c];
        M23l[i] = s;
    }
    __syncthreads();
    for (int i = t; i < DI * CO; i += blockDim.x) {
        int r = i / CO, c = i % CO;
        float s = 0.f;
        for (int k = 0; k < HH; ++k) s += W1[r * HH + k] * M23l[k * CO + c];
        Wf[i] = s;
    }
    if (t < CO) {
        float s1 = 0.f, s2 = 0.f, s3 = 0.f;
        for (int k = 0; k < HH; ++k) {
            s1 += b1[k] * M23l[k * CO + t];
            s2 += b2[k] * M3l[k * CO + t];
            s3 += b3[k] * Wl[k * CO + t];
        }
        cvec[t] = s1; cvec[CO + t] = s2; cvec[2 * CO + t] = s3;
    }
}

// ---------------- init: deg=1 (self loop), zero sums & cnt ----------------
__global__ void k_init(int* __restrict__ deg, float* __restrict__ sums, int* __restrict__ cnt) {
    int i = blockIdx.x * blockDim.x + threadIdx.x;
    if (i < NN) deg[i] = 1;
    if (i < GG * CO) sums[i] = 0.f;
    if (i < GG) cnt[i] = 0;
}

// ---------------- degree count over edges + per-graph node counts ----------------
__global__ void k_deg_cnt(const int* __restrict__ col, const int* __restrict__ batch,
                          int* __restrict__ deg, int* __restrict__ cnt) {
    int i = blockIdx.x * blockDim.x + threadIdx.x;
    if (i < EE) atomicAdd(&deg[col[i]], 1);
    if (i < NN) atomicAdd(&cnt[batch[i]], 1);
}

// ---------------- a0 = (X @ Wf) * dinv ; also store dinv, zero scatter buf ----------------
__global__ __launch_bounds__(256) void k_xw(const float* __restrict__ x, const float* __restrict__ Wf,
                                            const int* __restrict__ deg, float* __restrict__ dinv,
                                            float* __restrict__ as_, float* __restrict__ bbuf) {
    __shared__ float sWf[DI * CO];
    for (int i = threadIdx.x; i < DI * CO; i += blockDim.x) sWf[i] = Wf[i];
    __syncthreads();
    int n = blockIdx.x * blockDim.x + threadIdx.x;
    if (n >= NN) return;
    float acc[CO];
#pragma unroll
    for (int c = 0; c < CO; ++c) acc[c] = 0.f;
    const float4* xr = (const float4*)(x + (size_t)n * DI);
#pragma unroll 4
    for (int d4 = 0; d4 < DI / 4; ++d4) {
        float4 v = xr[d4];
        int d = d4 * 4;
#pragma unroll
        for (int c = 0; c < CO; ++c)
            acc[c] += v.x * sWf[(d + 0) * CO + c] + v.y * sWf[(d + 1) * CO + c]
                    + v.z * sWf[(d + 2) * CO + c] + v.w * sWf[(d + 3) * CO + c];
    }
    float di = rsqrtf((float)deg[n]);
    dinv[n] = di;
#pragma unroll
    for (int c = 0; c < CO; ++c) {
        as_[(size_t)n * CO + c] = acc[c] * di;
        bbuf[(size_t)n * CO + c] = 0.f;
    }
}

// ---------------- edge scatter: b[col] += as[row]  (as is pre-scaled by dinv[row]) ----------------
__global__ __launch_bounds__(256) void k_scatter(const int* __restrict__ row, const int* __restrict__ col,
                                                 const float* __restrict__ as_, float* __restrict__ bbuf) {
    int e = blockIdx.x * blockDim.x + threadIdx.x;
    if (e >= EE) return;
    int r = row[e], c = col[e];
    const float2* src = (const float2*)(as_ + (size_t)r * CO);  // 40B rows are 8B aligned
    float* dst = bbuf + (size_t)c * CO;
    float2 v0 = src[0], v1 = src[1], v2 = src[2], v3 = src[3], v4 = src[4];
    atomicAdd(dst + 0, v0.x); atomicAdd(dst + 1, v0.y);
    atomicAdd(dst + 2, v1.x); atomicAdd(dst + 3, v1.y);
    atomicAdd(dst + 4, v2.x); atomicAdd(dst + 5, v2.y);
    atomicAdd(dst + 6, v3.x); atomicAdd(dst + 7, v3.y);
    atomicAdd(dst + 8, v4.x); atomicAdd(dst + 9, v4.y);
}

// ---------------- finalize round k (k=1,2): as = (dinv*(b+as)+c_k)*dinv ; b=0 ----------------
__global__ __launch_bounds__(256) void k_finalize(const float* __restrict__ dinv, float* __restrict__ as_,
                                                  float* __restrict__ bbuf, const float* __restrict__ cvec,
                                                  int coff) {
    int n = blockIdx.x * blockDim.x + threadIdx.x;
    if (n >= NN) return;
    float di = dinv[n];
#pragma unroll
    for (int ch = 0; ch < CO; ++ch) {
        size_t idx = (size_t)n * CO + ch;
        float y = di * (bbuf[idx] + as_[idx]) + cvec[coff + ch];
        as_[idx] = y * di;
        bbuf[idx] = 0.f;
    }
}

// ---------------- final round + mean-pool accumulate ----------------
__global__ __launch_bounds__(256) void k_final_pool(const float* __restrict__ dinv, const float* __restrict__ as_,
                                                    const float* __restrict__ bbuf, const float* __restrict__ cvec,
                                                    const int* __restrict__ batch, float* __restrict__ sums) {
    int n = blockIdx.x * blockDim.x + threadIdx.x;
    if (n >= NN) return;
    float di = dinv[n];
    int g = batch[n];
#pragma unroll
    for (int ch = 0; ch < CO; ++ch) {
        size_t idx = (size_t)n * CO + ch;
        float y = di * (bbuf[idx] + as_[idx]) + cvec[2 * CO + ch];
        atomicAdd(&sums[(size_t)g * CO + ch], y);
    }
}

// ---------------- output: out = sums/max(cnt,1) + bl ----------------
__global__ void k_out(const float* __restrict__ sums, const int* __restrict__ cnt,
                      const float* __restrict__ bl, float* __restrict__ out) {
    int i = blockIdx.x * blockDim.x + threadIdx.x;
    if (i >= GG * CO) return;
    int g = i / CO, c = i % CO;
    out[i] = sums[i] / fmaxf((float)cnt[g], 1.f) + bl[c];
}

extern "C" void kernel_launch(void* const* d_in, const int* in_sizes, int n_in,
                              void* d_out, int out_size, void* d_ws, size_t ws_size,
                              hipStream_t stream) {
    const float* x    = (const float*)d_in[0];
    const int*   ei   = (const int*)d_in[1];     // (2, E) int32
    const int*   batch= (const int*)d_in[2];
    const float* W1   = (const float*)d_in[3];
    const float* b1   = (const float*)d_in[4];
    const float* W2   = (const float*)d_in[5];
    const float* b2   = (const float*)d_in[6];
    const float* W3   = (const float*)d_in[7];
    const float* b3   = (const float*)d_in[8];
    const float* Wl   = (const float*)d_in[9];
    const float* bl   = (const float*)d_in[10];
    float* out = (float*)d_out;

    const int* row = ei;        // edge_index[0]
    const int* col = ei + EE;   // edge_index[1]

    // carve workspace (element offsets, 64-elem aligned)
    float* ws = (float*)d_ws;
    size_t off = 0;
    auto alloc = [&](size_t elems) { size_t cur = off; off += (elems + 63) & ~(size_t)63; return cur; };
    float* Wf   = ws + alloc(DI * CO);
    float* cvec = ws + alloc(3 * CO);
    float* dinv = ws + alloc(NN);
    int*   deg  = (int*)(ws + alloc(NN));
    float* as_  = ws + alloc((size_t)NN * CO);
    float* bbuf = ws + alloc((size_t)NN * CO);
    float* sums = ws + alloc(GG * CO);
    int*   cnt  = (int*)(ws + alloc(GG));
    (void)ws_size; (void)in_sizes; (void)n_in; (void)out_size;

    const int BT = 256;
    int gN = (NN + BT - 1) / BT;
    int gE = (EE + BT - 1) / BT;

    hipLaunchKernelGGL(k_small_mats, dim3(1), dim3(256), 0, stream, W1, W2, W3, Wl, b1, b2, b3, Wf, cvec);
    hipLaunchKernelGGL(k_init, dim3(gN), dim3(BT), 0, stream, deg, sums, cnt);
    hipLaunchKernelGGL(k_deg_cnt, dim3(gE), dim3(BT), 0, stream, col, batch, deg, cnt);
    hipLaunchKernelGGL(k_xw, dim3(gN), dim3(BT), 0, stream, x, Wf, deg, dinv, as_, bbuf);

    // round 1
    hipLaunchKernelGGL(k_scatter, dim3(gE), dim3(BT), 0, stream, row, col, as_, bbuf);
    hipLaunchKernelGGL(k_finalize, dim3(gN), dim3(BT), 0, stream, dinv, as_, bbuf, cvec, 0);
    // round 2
    hipLaunchKernelGGL(k_scatter, dim3(gE), dim3(BT), 0, stream, row, col, as_, bbuf);
    hipLaunchKernelGGL(k_finalize, dim3(gN), dim3(BT), 0, stream, dinv, as_, bbuf, cvec, CO);
    // round 3 + pool
    hipLaunchKernelGGL(k_scatter, dim3(gE), dim3(BT), 0, stream, row, col, as_, bbuf);
    hipLaunchKernelGGL(k_final_pool, dim3(gN), dim3(BT), 0, stream, dinv, as_, bbuf, cvec, batch, sums);

    hipLaunchKernelGGL(k_out, dim3((GG * CO + BT - 1) / BT), dim3(BT), 0, stream, sums, cnt, bl, out);
}

// Round 3
// 649.002 us; speedup vs baseline: 4.2477x; 4.2477x over previous
//
#include <hip/hip_runtime.h>

#define NN 100000
#define EE 1600000
#define DI 128
#define HH 64
#define CO 10
#define GG 1024
#define LPN 8          // lanes cooperating per node in gather
#define SCAN_T 1024

// ---------------- tiny collapsed-weight kernel (1 block) ----------------
// Wf = W1@W2@W3@Wl (128x10), c1 = b1@W2@W3@Wl, c2 = b2@W3@Wl, c3 = b3@Wl
__global__ void k_small_mats(const float* __restrict__ W1, const float* __restrict__ W2,
                             const float* __restrict__ W3, const float* __restrict__ Wl,
                             const float* __restrict__ b1, const float* __restrict__ b2,
                             const float* __restrict__ b3,
                             float* __restrict__ Wf, float* __restrict__ cvec) {
    __shared__ float M3l[HH * CO];   // W3@Wl   (64x10)
    __shared__ float M23l[HH * CO];  // W2@M3l  (64x10)
    int t = threadIdx.x;
    for (int i = t; i < HH * CO; i += blockDim.x) {
        int r = i / CO, c = i % CO;
        float s = 0.f;
        for (int k = 0; k < HH; ++k) s += W3[r * HH + k] * Wl[k * CO + c];
        M3l[i] = s;
    }
    __syncthreads();
    for (int i = t; i < HH * CO; i += blockDim.x) {
        int r = i / CO, c = i % CO;
        float s = 0.f;
        for (int k = 0; k < HH; ++k) s += W2[r * HH + k] * M3l[k * CO + c];
        M23l[i] = s;
    }
    __syncthreads();
    for (int i = t; i < DI * CO; i += blockDim.x) {
        int r = i / CO, c = i % CO;
        float s = 0.f;
        for (int k = 0; k < HH; ++k) s += W1[r * HH + k] * M23l[k * CO + c];
        Wf[i] = s;
    }
    if (t < CO) {
        float s1 = 0.f, s2 = 0.f, s3 = 0.f;
        for (int k = 0; k < HH; ++k) {
            s1 += b1[k] * M23l[k * CO + t];
            s2 += b2[k] * M3l[k * CO + t];
            s3 += b3[k] * Wl[k * CO + t];
        }
        cvec[t] = s1; cvec[CO + t] = s2; cvec[2 * CO + t] = s3;
    }
}

// ---------------- zero in-degree counters ----------------
__global__ void k_init(int* __restrict__ deg) {
    int i = blockIdx.x * blockDim.x + threadIdx.x;
    if (i < NN) deg[i] = 0;
}

// ---------------- in-degree histogram (int atomics) ----------------
__global__ void k_hist(const int* __restrict__ col, int* __restrict__ deg) {
    int i = blockIdx.x * blockDim.x + threadIdx.x;
    if (i < EE) atomicAdd(&deg[col[i]], 1);
}

// ---------------- exclusive scan of counts -> rowptr (start offsets); dinv ----------------
__global__ __launch_bounds__(SCAN_T) void k_scan(const int* __restrict__ deg,
                                                 int* __restrict__ rowptr,
                                                 float* __restrict__ dinv) {
    __shared__ int ssum[SCAN_T];
    int t = threadIdx.x;
    const int K = (NN + SCAN_T - 1) / SCAN_T;  // 98
    int base = t * K;
    int local = 0;
    for (int i = 0; i < K; ++i) { int idx = base + i; if (idx < NN) local += deg[idx]; }
    ssum[t] = local;
    __syncthreads();
    for (int off = 1; off < SCAN_T; off <<= 1) {
        int v = (t >= off) ? ssum[t - off] : 0;
        __syncthreads();
        ssum[t] += v;
        __syncthreads();
    }
    int prefix = (t > 0) ? ssum[t - 1] : 0;  // exclusive
    for (int i = 0; i < K; ++i) {
        int idx = base + i;
        if (idx < NN) {
            int c = deg[idx];
            rowptr[idx] = prefix;
            prefix += c;
            dinv[idx] = rsqrtf((float)(c + 1));  // +1 self loop
        }
    }
}

// ---------------- graph boundaries via binary search (batch is sorted) ----------------
__global__ void k_gstart(const int* __restrict__ batch, int* __restrict__ gstart) {
    int g = blockIdx.x * blockDim.x + threadIdx.x;
    if (g > GG) return;
    int lo = 0, hi = NN;
    while (lo < hi) { int mid = (lo + hi) >> 1; if (batch[mid] < g) lo = mid + 1; else hi = mid; }
    gstart[g] = lo;
}

// ---------------- place edges into CSR (rowptr mutates start->end) ----------------
__global__ void k_place(const int* __restrict__ row, const int* __restrict__ col,
                        int* __restrict__ rowptr, int* __restrict__ srcIdx) {
    int e = blockIdx.x * blockDim.x + threadIdx.x;
    if (e >= EE) return;
    int c = col[e];
    int pos = atomicAdd(&rowptr[c], 1);
    srcIdx[pos] = row[e];
}

// ---------------- a0 = (X @ Wf) * dinv ----------------
__global__ __launch_bounds__(256) void k_xw(const float* __restrict__ x, const float* __restrict__ Wf,
                                            const float* __restrict__ dinv,
                                            float* __restrict__ as_) {
    __shared__ float sWf[DI * CO];
    for (int i = threadIdx.x; i < DI * CO; i += blockDim.x) sWf[i] = Wf[i];
    __syncthreads();
    int n = blockIdx.x * blockDim.x + threadIdx.x;
    if (n >= NN) return;
    float acc[CO];
#pragma unroll
    for (int c = 0; c < CO; ++c) acc[c] = 0.f;
    const float4* xr = (const float4*)(x + (size_t)n * DI);
#pragma unroll 4
    for (int d4 = 0; d4 < DI / 4; ++d4) {
        float4 v = xr[d4];
        int d = d4 * 4;
#pragma unroll
        for (int c = 0; c < CO; ++c)
            acc[c] += v.x * sWf[(d + 0) * CO + c] + v.y * sWf[(d + 1) * CO + c]
                    + v.z * sWf[(d + 2) * CO + c] + v.w * sWf[(d + 3) * CO + c];
    }
    float di = dinv[n];
#pragma unroll
    for (int c = 0; c < CO; ++c) as_[(size_t)n * CO + c] = acc[c] * di;
}

// ---------------- gather round: dst[n] = f(sum_{e in CSR(n)} src[srcIdx[e]] + src[n]) ----------------
// src rows are pre-scaled by dinv[src]; y = dinv[n]*(sum+self)+c; non-final rounds pre-scale by dinv[n].
template <int FINAL>
__global__ __launch_bounds__(256) void k_gather(const int* __restrict__ rowptr_end,
                                                const int* __restrict__ srcIdx,
                                                const float* __restrict__ src,
                                                const float* __restrict__ dinv,
                                                const float* __restrict__ cvec, int coff,
                                                float* __restrict__ dst) {
    int gid = blockIdx.x * blockDim.x + threadIdx.x;
    int n = gid / LPN;
    int l = threadIdx.x & (LPN - 1);
    if (n >= NN) return;
    int beg = (n == 0) ? 0 : rowptr_end[n - 1];
    int end = rowptr_end[n];
    float acc[CO];
#pragma unroll
    for (int c = 0; c < CO; ++c) acc[c] = 0.f;
    for (int e = beg + l; e < end; e += LPN) {
        int s = srcIdx[e];
        const float2* sp = (const float2*)(src + (size_t)s * CO);
        float2 a = sp[0], b = sp[1], c2 = sp[2], d = sp[3], f = sp[4];
        acc[0] += a.x; acc[1] += a.y; acc[2] += b.x; acc[3] += b.y; acc[4] += c2.x;
        acc[5] += c2.y; acc[6] += d.x; acc[7] += d.y; acc[8] += f.x; acc[9] += f.y;
    }
#pragma unroll
    for (int m = 1; m < LPN; m <<= 1) {
#pragma unroll
        for (int c = 0; c < CO; ++c) acc[c] += __shfl_xor(acc[c], m, 64);
    }
    if (l == 0) {
        float di = dinv[n];
        const float* selfp = src + (size_t)n * CO;
        float o[CO];
#pragma unroll
        for (int c = 0; c < CO; ++c) {
            float y = di * (acc[c] + selfp[c]) + cvec[coff + c];
            o[c] = FINAL ? y : y * di;
        }
        float2* dp = (float2*)(dst + (size_t)n * CO);
#pragma unroll
        for (int i = 0; i < 5; ++i) dp[i] = make_float2(o[2 * i], o[2 * i + 1]);
    }
}

// ---------------- mean-pool per graph + bl; one wave per graph ----------------
__global__ __launch_bounds__(64) void k_pool(const float* __restrict__ h,
                                             const int* __restrict__ gstart,
                                             const float* __restrict__ bl,
                                             float* __restrict__ out) {
    int g = blockIdx.x;
    int beg = gstart[g], end = gstart[g + 1];
    int l = threadIdx.x;
    float acc[CO];
#pragma unroll
    for (int c = 0; c < CO; ++c) acc[c] = 0.f;
    for (int n = beg + l; n < end; n += 64) {
        const float2* sp = (const float2*)(h + (size_t)n * CO);
        float2 a = sp[0], b = sp[1], c2 = sp[2], d = sp[3], f = sp[4];
        acc[0] += a.x; acc[1] += a.y; acc[2] += b.x; acc[3] += b.y; acc[4] += c2.x;
        acc[5] += c2.y; acc[6] += d.x; acc[7] += d.y; acc[8] += f.x; acc[9] += f.y;
    }
#pragma unroll
    for (int m = 1; m < 64; m <<= 1) {
#pragma unroll
        for (int c = 0; c < CO; ++c) acc[c] += __shfl_xor(acc[c], m, 64);
    }
    if (l == 0) {
        float cf = fmaxf((float)(end - beg), 1.f);
#pragma unroll
        for (int c = 0; c < CO; ++c) out[(size_t)g * CO + c] = acc[c] / cf + bl[c];
    }
}

extern "C" void kernel_launch(void* const* d_in, const int* in_sizes, int n_in,
                              void* d_out, int out_size, void* d_ws, size_t ws_size,
                              hipStream_t stream) {
    const float* x    = (const float*)d_in[0];
    const int*   ei   = (const int*)d_in[1];     // (2, E) int32
    const int*   batch= (const int*)d_in[2];
    const float* W1   = (const float*)d_in[3];
    const float* b1   = (const float*)d_in[4];
    const float* W2   = (const float*)d_in[5];
    const float* b2   = (const float*)d_in[6];
    const float* W3   = (const float*)d_in[7];
    const float* b3   = (const float*)d_in[8];
    const float* Wl   = (const float*)d_in[9];
    const float* bl   = (const float*)d_in[10];
    float* out = (float*)d_out;

    const int* row = ei;        // edge_index[0]
    const int* col = ei + EE;   // edge_index[1]

    float* ws = (float*)d_ws;
    size_t off = 0;
    auto alloc = [&](size_t elems) { size_t cur = off; off += (elems + 63) & ~(size_t)63; return cur; };
    float* Wf     = ws + alloc(DI * CO);
    float* cvec   = ws + alloc(3 * CO);
    float* dinv   = ws + alloc(NN);
    int*   deg    = (int*)(ws + alloc(NN));
    int*   rowptr = (int*)(ws + alloc(NN));
    int*   srcIdx = (int*)(ws + alloc(EE));
    float* as_    = ws + alloc((size_t)NN * CO);
    float* bbuf   = ws + alloc((size_t)NN * CO);
    int*   gstart = (int*)(ws + alloc(GG + 1));
    (void)ws_size; (void)in_sizes; (void)n_in; (void)out_size;

    const int BT = 256;
    int gN = (NN + BT - 1) / BT;
    int gE = (EE + BT - 1) / BT;
    int gNL = ((NN * LPN) + BT - 1) / BT;

    hipLaunchKernelGGL(k_small_mats, dim3(1), dim3(256), 0, stream, W1, W2, W3, Wl, b1, b2, b3, Wf, cvec);
    hipLaunchKernelGGL(k_init, dim3(gN), dim3(BT), 0, stream, deg);
    hipLaunchKernelGGL(k_hist, dim3(gE), dim3(BT), 0, stream, col, deg);
    hipLaunchKernelGGL(k_scan, dim3(1), dim3(SCAN_T), 0, stream, deg, rowptr, dinv);
    hipLaunchKernelGGL(k_gstart, dim3((GG + 1 + BT - 1) / BT), dim3(BT), 0, stream, batch, gstart);
    hipLaunchKernelGGL(k_place, dim3(gE), dim3(BT), 0, stream, row, col, rowptr, srcIdx);
    hipLaunchKernelGGL(k_xw, dim3(gN), dim3(BT), 0, stream, x, Wf, dinv, as_);

    hipLaunchKernelGGL((k_gather<0>), dim3(gNL), dim3(BT), 0, stream, rowptr, srcIdx, as_,  dinv, cvec, 0,      bbuf);
    hipLaunchKernelGGL((k_gather<0>), dim3(gNL), dim3(BT), 0, stream, rowptr, srcIdx, bbuf, dinv, cvec, CO,     as_);
    hipLaunchKernelGGL((k_gather<1>), dim3(gNL), dim3(BT), 0, stream, rowptr, srcIdx, as_,  dinv, cvec, 2 * CO, bbuf);

    hipLaunchKernelGGL(k_pool, dim3(GG), dim3(64), 0, stream, bbuf, gstart, bl, out);
}

// Round 4
// 396.045 us; speedup vs baseline: 6.9607x; 1.6387x over previous
//
#include <hip/hip_runtime.h>

#define NN 100000
#define EE 1600000
#define DI 128
#define HH 64
#define CO 10
#define GG 1024
#define LPN 8          // lanes cooperating per node in gather
#define SCB 1024       // scan block size
#define NBS ((NN + SCB - 1) / SCB)   // 98 scan blocks

// ---------------- tiny collapsed-weight kernel (1 block) ----------------
// Wf = W1@W2@W3@Wl (128x10), c1 = b1@W2@W3@Wl, c2 = b2@W3@Wl, c3 = b3@Wl
__global__ void k_small_mats(const float* __restrict__ W1, const float* __restrict__ W2,
                             const float* __restrict__ W3, const float* __restrict__ Wl,
                             const float* __restrict__ b1, const float* __restrict__ b2,
                             const float* __restrict__ b3,
                             float* __restrict__ Wf, float* __restrict__ cvec) {
    __shared__ float M3l[HH * CO];   // W3@Wl   (64x10)
    __shared__ float M23l[HH * CO];  // W2@M3l  (64x10)
    int t = threadIdx.x;
    for (int i = t; i < HH * CO; i += blockDim.x) {
        int r = i / CO, c = i % CO;
        float s = 0.f;
        for (int k = 0; k < HH; ++k) s += W3[r * HH + k] * Wl[k * CO + c];
        M3l[i] = s;
    }
    __syncthreads();
    for (int i = t; i < HH * CO; i += blockDim.x) {
        int r = i / CO, c = i % CO;
        float s = 0.f;
        for (int k = 0; k < HH; ++k) s += W2[r * HH + k] * M3l[k * CO + c];
        M23l[i] = s;
    }
    __syncthreads();
    for (int i = t; i < DI * CO; i += blockDim.x) {
        int r = i / CO, c = i % CO;
        float s = 0.f;
        for (int k = 0; k < HH; ++k) s += W1[r * HH + k] * M23l[k * CO + c];
        Wf[i] = s;
    }
    if (t < CO) {
        float s1 = 0.f, s2 = 0.f, s3 = 0.f;
        for (int k = 0; k < HH; ++k) {
            s1 += b1[k] * M23l[k * CO + t];
            s2 += b2[k] * M3l[k * CO + t];
            s3 += b3[k] * Wl[k * CO + t];
        }
        cvec[t] = s1; cvec[CO + t] = s2; cvec[2 * CO + t] = s3;
    }
}

// ---------------- zero in-degree counters ----------------
__global__ void k_init(int* __restrict__ deg) {
    int i = blockIdx.x * blockDim.x + threadIdx.x;
    if (i < NN) deg[i] = 0;
}

// ---------------- in-degree histogram (int atomics) ----------------
__global__ void k_hist(const int* __restrict__ col, int* __restrict__ deg) {
    int i = blockIdx.x * blockDim.x + threadIdx.x;
    if (i < EE) atomicAdd(&deg[col[i]], 1);
}

// ---------------- hierarchical scan phase A: per-block exclusive scan + block sums; dinv ----------------
__global__ __launch_bounds__(SCB) void k_scanA(const int* __restrict__ deg,
                                               int* __restrict__ rowptr,
                                               float* __restrict__ dinv,
                                               int* __restrict__ bsum) {
    __shared__ int s[SCB];
    int t = threadIdx.x;
    int idx = blockIdx.x * SCB + t;
    int v = (idx < NN) ? deg[idx] : 0;
    s[t] = v;
    __syncthreads();
    for (int off = 1; off < SCB; off <<= 1) {
        int u = (t >= off) ? s[t - off] : 0;
        __syncthreads();
        s[t] += u;
        __syncthreads();
    }
    if (idx < NN) {
        rowptr[idx] = s[t] - v;                 // exclusive within block
        dinv[idx] = rsqrtf((float)(v + 1));     // +1 self loop
    }
    if (t == SCB - 1) bsum[blockIdx.x] = s[t];
}

// ---------------- phase B: exclusive scan of 98 block sums (1 tiny block) ----------------
__global__ __launch_bounds__(128) void k_scanB(int* __restrict__ bsum) {
    __shared__ int s[128];
    int t = threadIdx.x;
    int v = (t < NBS) ? bsum[t] : 0;
    s[t] = v;
    __syncthreads();
    for (int off = 1; off < 128; off <<= 1) {
        int u = (t >= off) ? s[t - off] : 0;
        __syncthreads();
        s[t] += u;
        __syncthreads();
    }
    if (t < NBS) bsum[t] = s[t] - v;            // exclusive
}

// ---------------- phase C: add block offsets ----------------
__global__ __launch_bounds__(SCB) void k_scanC(int* __restrict__ rowptr, const int* __restrict__ bsum) {
    int idx = blockIdx.x * SCB + threadIdx.x;
    if (idx < NN) rowptr[idx] += bsum[blockIdx.x];
}

// ---------------- graph boundaries via binary search (batch is sorted) ----------------
__global__ void k_gstart(const int* __restrict__ batch, int* __restrict__ gstart) {
    int g = blockIdx.x * blockDim.x + threadIdx.x;
    if (g > GG) return;
    int lo = 0, hi = NN;
    while (lo < hi) { int mid = (lo + hi) >> 1; if (batch[mid] < g) lo = mid + 1; else hi = mid; }
    gstart[g] = lo;
}

// ---------------- place edges into CSR (rowptr mutates start->end) ----------------
__global__ void k_place(const int* __restrict__ row, const int* __restrict__ col,
                        int* __restrict__ rowptr, int* __restrict__ srcIdx) {
    int e = blockIdx.x * blockDim.x + threadIdx.x;
    if (e >= EE) return;
    int c = col[e];
    int pos = atomicAdd(&rowptr[c], 1);
    srcIdx[pos] = row[e];
}

// ---------------- a0 = (X @ Wf) * dinv ----------------
__global__ __launch_bounds__(256) void k_xw(const float* __restrict__ x, const float* __restrict__ Wf,
                                            const float* __restrict__ dinv,
                                            float* __restrict__ as_) {
    __shared__ float sWf[DI * CO];
    for (int i = threadIdx.x; i < DI * CO; i += blockDim.x) sWf[i] = Wf[i];
    __syncthreads();
    int n = blockIdx.x * blockDim.x + threadIdx.x;
    if (n >= NN) return;
    float acc[CO];
#pragma unroll
    for (int c = 0; c < CO; ++c) acc[c] = 0.f;
    const float4* xr = (const float4*)(x + (size_t)n * DI);
#pragma unroll 4
    for (int d4 = 0; d4 < DI / 4; ++d4) {
        float4 v = xr[d4];
        int d = d4 * 4;
#pragma unroll
        for (int c = 0; c < CO; ++c)
            acc[c] += v.x * sWf[(d + 0) * CO + c] + v.y * sWf[(d + 1) * CO + c]
                    + v.z * sWf[(d + 2) * CO + c] + v.w * sWf[(d + 3) * CO + c];
    }
    float di = dinv[n];
#pragma unroll
    for (int c = 0; c < CO; ++c) as_[(size_t)n * CO + c] = acc[c] * di;
}

// ---------------- gather round: dst[n] = f(sum_{e in CSR(n)} src[srcIdx[e]] + src[n]) ----------------
// src rows pre-scaled by dinv[src]; y = dinv[n]*(sum+self)+c; non-final rounds pre-scale by dinv[n].
template <int FINAL>
__global__ __launch_bounds__(256) void k_gather(const int* __restrict__ rowptr_end,
                                                const int* __restrict__ srcIdx,
                                                const float* __restrict__ src,
                                                const float* __restrict__ dinv,
                                                const float* __restrict__ cvec, int coff,
                                                float* __restrict__ dst) {
    int gid = blockIdx.x * blockDim.x + threadIdx.x;
    int n = gid / LPN;
    int l = threadIdx.x & (LPN - 1);
    if (n >= NN) return;
    int beg = (n == 0) ? 0 : rowptr_end[n - 1];
    int end = rowptr_end[n];
    float acc[CO];
#pragma unroll
    for (int c = 0; c < CO; ++c) acc[c] = 0.f;
    for (int e = beg + l; e < end; e += LPN) {
        int s = srcIdx[e];
        const float2* sp = (const float2*)(src + (size_t)s * CO);
        float2 a = sp[0], b = sp[1], c2 = sp[2], d = sp[3], f = sp[4];
        acc[0] += a.x; acc[1] += a.y; acc[2] += b.x; acc[3] += b.y; acc[4] += c2.x;
        acc[5] += c2.y; acc[6] += d.x; acc[7] += d.y; acc[8] += f.x; acc[9] += f.y;
    }
#pragma unroll
    for (int m = 1; m < LPN; m <<= 1) {
#pragma unroll
        for (int c = 0; c < CO; ++c) acc[c] += __shfl_xor(acc[c], m, 64);
    }
    if (l == 0) {
        float di = dinv[n];
        const float* selfp = src + (size_t)n * CO;
        float o[CO];
#pragma unroll
        for (int c = 0; c < CO; ++c) {
            float y = di * (acc[c] + selfp[c]) + cvec[coff + c];
            o[c] = FINAL ? y : y * di;
        }
        float2* dp = (float2*)(dst + (size_t)n * CO);
#pragma unroll
        for (int i = 0; i < 5; ++i) dp[i] = make_float2(o[2 * i], o[2 * i + 1]);
    }
}

// ---------------- mean-pool per graph + bl; one wave per graph ----------------
__global__ __launch_bounds__(64) void k_pool(const float* __restrict__ h,
                                             const int* __restrict__ gstart,
                                             const float* __restrict__ bl,
                                             float* __restrict__ out) {
    int g = blockIdx.x;
    int beg = gstart[g], end = gstart[g + 1];
    int l = threadIdx.x;
    float acc[CO];
#pragma unroll
    for (int c = 0; c < CO; ++c) acc[c] = 0.f;
    for (int n = beg + l; n < end; n += 64) {
        const float2* sp = (const float2*)(h + (size_t)n * CO);
        float2 a = sp[0], b = sp[1], c2 = sp[2], d = sp[3], f = sp[4];
        acc[0] += a.x; acc[1] += a.y; acc[2] += b.x; acc[3] += b.y; acc[4] += c2.x;
        acc[5] += c2.y; acc[6] += d.x; acc[7] += d.y; acc[8] += f.x; acc[9] += f.y;
    }
#pragma unroll
    for (int m = 1; m < 64; m <<= 1) {
#pragma unroll
        for (int c = 0; c < CO; ++c) acc[c] += __shfl_xor(acc[c], m, 64);
    }
    if (l == 0) {
        float cf = fmaxf((float)(end - beg), 1.f);
#pragma unroll
        for (int c = 0; c < CO; ++c) out[(size_t)g * CO + c] = acc[c] / cf + bl[c];
    }
}

extern "C" void kernel_launch(void* const* d_in, const int* in_sizes, int n_in,
                              void* d_out, int out_size, void* d_ws, size_t ws_size,
                              hipStream_t stream) {
    const float* x    = (const float*)d_in[0];
    const int*   ei   = (const int*)d_in[1];     // (2, E) int32
    const int*   batch= (const int*)d_in[2];
    const float* W1   = (const float*)d_in[3];
    const float* b1   = (const float*)d_in[4];
    const float* W2   = (const float*)d_in[5];
    const float* b2   = (const float*)d_in[6];
    const float* W3   = (const float*)d_in[7];
    const float* b3   = (const float*)d_in[8];
    const float* Wl   = (const float*)d_in[9];
    const float* bl   = (const float*)d_in[10];
    float* out = (float*)d_out;

    const int* row = ei;        // edge_index[0]
    const int* col = ei + EE;   // edge_index[1]

    float* ws = (float*)d_ws;
    size_t off = 0;
    auto alloc = [&](size_t elems) { size_t cur = off; off += (elems + 63) & ~(size_t)63; return cur; };
    float* Wf     = ws + alloc(DI * CO);
    float* cvec   = ws + alloc(3 * CO);
    float* dinv   = ws + alloc(NN);
    int*   deg    = (int*)(ws + alloc(NN));
    int*   rowptr = (int*)(ws + alloc(NN));
    int*   srcIdx = (int*)(ws + alloc(EE));
    float* as_    = ws + alloc((size_t)NN * CO);
    float* bbuf   = ws + alloc((size_t)NN * CO);
    int*   gstart = (int*)(ws + alloc(GG + 1));
    int*   bsum   = (int*)(ws + alloc(128));
    (void)ws_size; (void)in_sizes; (void)n_in; (void)out_size;

    const int BT = 256;
    int gN = (NN + BT - 1) / BT;
    int gE = (EE + BT - 1) / BT;
    int gNL = ((NN * LPN) + BT - 1) / BT;

    hipLaunchKernelGGL(k_small_mats, dim3(1), dim3(256), 0, stream, W1, W2, W3, Wl, b1, b2, b3, Wf, cvec);
    hipLaunchKernelGGL(k_init, dim3(gN), dim3(BT), 0, stream, deg);
    hipLaunchKernelGGL(k_hist, dim3(gE), dim3(BT), 0, stream, col, deg);
    hipLaunchKernelGGL(k_scanA, dim3(NBS), dim3(SCB), 0, stream, deg, rowptr, dinv, bsum);
    hipLaunchKernelGGL(k_scanB, dim3(1), dim3(128), 0, stream, bsum);
    hipLaunchKernelGGL(k_scanC, dim3(NBS), dim3(SCB), 0, stream, rowptr, bsum);
    hipLaunchKernelGGL(k_gstart, dim3((GG + 1 + BT - 1) / BT), dim3(BT), 0, stream, batch, gstart);
    hipLaunchKernelGGL(k_place, dim3(gE), dim3(BT), 0, stream, row, col, rowptr, srcIdx);
    hipLaunchKernelGGL(k_xw, dim3(gN), dim3(BT), 0, stream, x, Wf, dinv, as_);

    hipLaunchKernelGGL((k_gather<0>), dim3(gNL), dim3(BT), 0, stream, rowptr, srcIdx, as_,  dinv, cvec, 0,      bbuf);
    hipLaunchKernelGGL((k_gather<0>), dim3(gNL), dim3(BT), 0, stream, rowptr, srcIdx, bbuf, dinv, cvec, CO,     as_);
    hipLaunchKernelGGL((k_gather<1>), dim3(gNL), dim3(BT), 0, stream, rowptr, srcIdx, as_,  dinv, cvec, 2 * CO, bbuf);

    hipLaunchKernelGGL(k_pool, dim3(GG), dim3(64), 0, stream, bbuf, gstart, bl, out);
}